// Round 12
// baseline (2217.780 us; speedup 1.0000x reference)
//
#include <hip/hip_runtime.h>
#include <hip/hip_bf16.h>

#define N_NODES 50000
#define N_EDGES 800000
#define IN_DIM  64
#define HID_DIM 128
#define OUT_DIM 32
#define ELLW    64    // max supported degree; P(max_deg>64) ~ 1e-13 for this graph

#define NBKT   8                       // dst buckets (node ranges of 6250)
#define NWG    8                       // writer groups (XCD-private append)
#define RNG    (N_NODES / NBKT)        // 6250
#define SBCAP  13500                   // sub-bucket capacity: mean 12500, ~9 sigma slack

#define BIN_BLKS  3125   // 800000 edges / 256 (1 edge/thread)
#define CAST_BLKS 3125   // 800000 float4 / 256
#define PW1_BLKS  32     // 64*128/256
#define PW2_BLKS  64     // 128*128/256
#define PWO_BLKS  16     // 128*32/256
#define PREP_BLKS (CAST_BLKS + PW1_BLKS + PW2_BLKS + PWO_BLKS)   // 3237
#define ELLB_BLKS 1024   // 8 buckets x 8 groups x 16 slices

typedef short bh8_t  __attribute__((ext_vector_type(8)));   // 8 bf16 (4 VGPRs)
typedef float fx4_t  __attribute__((ext_vector_type(4)));   // MFMA acc

// bf16 helpers (raw-bit, header-version independent)
__device__ inline float bflo(unsigned int u) {
    union { unsigned int i; float f; } c; c.i = u << 16; return c.f;
}
__device__ inline float bfhi(unsigned int u) {
    union { unsigned int i; float f; } c; c.i = u & 0xffff0000u; return c.f;
}
__device__ inline unsigned short f2bf(float f) {   // round-to-nearest-even
    union { float f; unsigned int i; } c; c.f = f;
    unsigned int u = c.i;
    u += 0x7fffu + ((u >> 16) & 1u);
    return (unsigned short)(u >> 16);
}
__device__ inline unsigned int pack2(float a, float b) {
    return (unsigned int)f2bf(a) | ((unsigned int)f2bf(b) << 16);
}
__device__ inline void acc_u2(float* a, uint2 u) {
    a[0] += bflo(u.x); a[1] += bfhi(u.x);
    a[2] += bflo(u.y); a[3] += bfhi(u.y);
}
__device__ inline void acc_u4(float* a, uint4 u) {
    a[0] += bflo(u.x); a[1] += bfhi(u.x);
    a[2] += bflo(u.y); a[3] += bfhi(u.y);
    a[4] += bflo(u.z); a[5] += bfhi(u.z);
    a[6] += bflo(u.w); a[7] += bfhi(u.w);
}

template <int K, int M>
__device__ inline void packw_one(const float* __restrict__ W,
                                 unsigned short* __restrict__ Wp, int f) {
    const int k = f / M, m = f % M;
    Wp[((k >> 3) * M + m) * 8 + (k & 7)] = f2bf(W[f]);
}

// ---------------------------------------------------------------------------
// K0: fused edge-binning + prep.  bcnt zeroed beforehand (with cnt, 1 memset).
//     Blocks [0, BIN_BLKS): 1 edge/thread; append (src,dst) into sub-bucket
//       (b = dst/6250, g = blockIdx&7).  g follows the round-robin block->XCD
//       mapping, so each sub-bucket's append region is written by ONE XCD,
//       and appends are dense -> only the tail line is hot -> no write
//       amplification (unlike direct ELL scatter, whose per-node writes are
//       spread across the whole pass and evict between touches).
//     Blocks [BIN_BLKS, +PREP_BLKS): cast x->bf16, pack W1/W2/Wout.
// ---------------------------------------------------------------------------
__global__ __launch_bounds__(256) void k_bin(const int* __restrict__ src,
                                             const int* __restrict__ dst,
                                             int* __restrict__ bcnt,
                                             int2* __restrict__ bins,
                                             const float* __restrict__ x,
                                             unsigned short* __restrict__ xb,
                                             const float* __restrict__ W1,
                                             unsigned short* __restrict__ wp1,
                                             const float* __restrict__ W2,
                                             unsigned short* __restrict__ wp2,
                                             const float* __restrict__ Wout,
                                             unsigned short* __restrict__ wpo) {
    const int bid = blockIdx.x;
    if (bid < BIN_BLKS) {
        const int g = bid & (NWG - 1);
        const int e = bid * 256 + threadIdx.x;   // 3125*256 = 800000 exact
        const int d = dst[e];
        const int s = src[e];
        const int sb = (d / RNG) * NWG + g;
        const int p = atomicAdd(&bcnt[sb], 1);
        if (p < SBCAP) bins[(size_t)sb * SBCAP + p] = make_int2(s, d);
        return;
    }
    const int pb = bid - BIN_BLKS;
    if (pb < CAST_BLKS) {
        const int i = pb * 256 + threadIdx.x;    // exactly 800000 float4s
        float4 v = reinterpret_cast<const float4*>(x)[i];
        ushort4 o;
        o.x = f2bf(v.x); o.y = f2bf(v.y); o.z = f2bf(v.z); o.w = f2bf(v.w);
        reinterpret_cast<ushort4*>(xb)[i] = o;
    } else if (pb < CAST_BLKS + PW1_BLKS) {
        packw_one<IN_DIM, HID_DIM>(W1, wp1, (pb - CAST_BLKS) * 256 + threadIdx.x);
    } else if (pb < CAST_BLKS + PW1_BLKS + PW2_BLKS) {
        packw_one<HID_DIM, HID_DIM>(W2, wp2, (pb - CAST_BLKS - PW1_BLKS) * 256 + threadIdx.x);
    } else {
        packw_one<HID_DIM, OUT_DIM>(Wout, wpo,
                                    (pb - CAST_BLKS - PW1_BLKS - PW2_BLKS) * 256 + threadIdx.x);
    }
}

// ---------------------------------------------------------------------------
// K0b: ELL build from bins.  Bucket b is processed ONLY by blocks with
//      bid&7 == b (one XCD), all within one short window -> each node's
//      256B ELL row accumulates its ~16 writes while the bucket's 1.6MB
//      footprint is L2-resident.  cnt atomics are XCD-local too.
// ---------------------------------------------------------------------------
__global__ __launch_bounds__(256) void k_ellb(const int2* __restrict__ bins,
                                              const int* __restrict__ bcnt,
                                              int* __restrict__ cnt,
                                              int* __restrict__ ell) {
    const int b = blockIdx.x & (NBKT - 1);
    const int g = (blockIdx.x >> 3) & (NWG - 1);
    const int j = blockIdx.x >> 6;              // 0..15
    const int sb = b * NWG + g;
    const int cg = min(bcnt[sb], SBCAP);
    const int2* bb = bins + (size_t)sb * SBCAP;
    for (int i = j * 256 + threadIdx.x; i < cg; i += 16 * 256) {
        const int2 e = bb[i];
        const int p = atomicAdd(&cnt[e.y], 1);
        if (p < ELLW) ell[(size_t)e.y * ELLW + p] = e.x;
    }
}

// ---------------------------------------------------------------------------
// K1: layer-1 aggregation (64-dim) over ELL; 16 lanes/node, 8-edge pipeline.
//     m1b = bf16(mean of neighbor xb rows), fp32 acc.
// ---------------------------------------------------------------------------
__global__ __launch_bounds__(256) void k_agg1(const unsigned short* __restrict__ Xb,
                                              const int* __restrict__ ell,
                                              const int* __restrict__ cnt,
                                              unsigned short* __restrict__ Mb) {
    const int gid  = threadIdx.x >> 4;
    const int lane = threadIdx.x & 15;
    const int node = blockIdx.x * 16 + gid;     // grid 3125*16 = 50000 exact
    const int c = min(cnt[node], ELLW);
    const float r = (c > 0) ? 1.0f / (float)c : 0.0f;
    const int* er = ell + (size_t)node * ELLW;
    const unsigned short* base = Xb + lane * 4;

    float a0[4], a1[4];
#pragma unroll
    for (int v = 0; v < 4; ++v) { a0[v] = 0.f; a1[v] = 0.f; }

    int j = 0;
    for (; j + 8 <= c; j += 8) {
        const int4 e03 = *reinterpret_cast<const int4*>(er + j);
        const int4 e47 = *reinterpret_cast<const int4*>(er + j + 4);
        uint2 u0 = *reinterpret_cast<const uint2*>(base + (size_t)e03.x * IN_DIM);
        uint2 u1 = *reinterpret_cast<const uint2*>(base + (size_t)e03.y * IN_DIM);
        uint2 u2 = *reinterpret_cast<const uint2*>(base + (size_t)e03.z * IN_DIM);
        uint2 u3 = *reinterpret_cast<const uint2*>(base + (size_t)e03.w * IN_DIM);
        uint2 u4 = *reinterpret_cast<const uint2*>(base + (size_t)e47.x * IN_DIM);
        uint2 u5 = *reinterpret_cast<const uint2*>(base + (size_t)e47.y * IN_DIM);
        uint2 u6 = *reinterpret_cast<const uint2*>(base + (size_t)e47.z * IN_DIM);
        uint2 u7 = *reinterpret_cast<const uint2*>(base + (size_t)e47.w * IN_DIM);
        acc_u2(a0, u0); acc_u2(a1, u1); acc_u2(a0, u2); acc_u2(a1, u3);
        acc_u2(a0, u4); acc_u2(a1, u5); acc_u2(a0, u6); acc_u2(a1, u7);
    }
    for (; j + 4 <= c; j += 4) {
        const int4 e4 = *reinterpret_cast<const int4*>(er + j);
        uint2 u0 = *reinterpret_cast<const uint2*>(base + (size_t)e4.x * IN_DIM);
        uint2 u1 = *reinterpret_cast<const uint2*>(base + (size_t)e4.y * IN_DIM);
        uint2 u2 = *reinterpret_cast<const uint2*>(base + (size_t)e4.z * IN_DIM);
        uint2 u3 = *reinterpret_cast<const uint2*>(base + (size_t)e4.w * IN_DIM);
        acc_u2(a0, u0); acc_u2(a1, u1); acc_u2(a0, u2); acc_u2(a1, u3);
    }
    for (; j < c; ++j) {
        uint2 u = *reinterpret_cast<const uint2*>(base + (size_t)er[j] * IN_DIM);
        acc_u2(a0, u);
    }

    uint2 o;
    o.x = pack2((a0[0] + a1[0]) * r, (a0[1] + a1[1]) * r);
    o.y = pack2((a0[2] + a1[2]) * r, (a0[3] + a1[3]) * r);
    *reinterpret_cast<uint2*>(Mb + (size_t)node * IN_DIM + lane * 4) = o;
}

// ---------------------------------------------------------------------------
// K2: layer-1 MFMA GEMM.  h1b = bf16(relu(m1b @ wp1 + b1)), masked by cnt.
// ---------------------------------------------------------------------------
__global__ __launch_bounds__(256) void k_mgemm1(const unsigned short* __restrict__ A,
                                                const unsigned short* __restrict__ Wpg,
                                                const float* __restrict__ b1,
                                                const int* __restrict__ cnt,
                                                unsigned short* __restrict__ h1b) {
    __shared__ unsigned short Wp[IN_DIM * HID_DIM];   // 16 KB
    const int tid = threadIdx.x;
#pragma unroll
    for (int f = tid; f < IN_DIM * HID_DIM / 8; f += 256)
        reinterpret_cast<uint4*>(Wp)[f] = reinterpret_cast<const uint4*>(Wpg)[f];
    __syncthreads();

    const int w  = tid >> 6;
    const int l  = tid & 63;
    const int lr = l & 15;
    const int lg = l >> 4;
    const int row = blockIdx.x * 64 + w * 16 + lr;
    const bool rok = row < N_NODES;
    const unsigned short* Arow = A + (size_t)row * IN_DIM;

    fx4_t acc[8];
#pragma unroll
    for (int ct = 0; ct < 8; ++ct) acc[ct] = (fx4_t){0.f, 0.f, 0.f, 0.f};

#pragma unroll
    for (int kc = 0; kc < IN_DIM; kc += 32) {
        bh8_t af = {};
        if (rok) af = *reinterpret_cast<const bh8_t*>(Arow + kc + lg * 8);
#pragma unroll
        for (int ct = 0; ct < 8; ++ct) {
            const bh8_t bf = *reinterpret_cast<const bh8_t*>(
                &Wp[(((kc >> 3) + lg) * HID_DIM + ct * 16 + lr) * 8]);
            acc[ct] = __builtin_amdgcn_mfma_f32_16x16x32_bf16(af, bf, acc[ct], 0, 0, 0);
        }
    }

    const int orow0 = blockIdx.x * 64 + w * 16 + lg * 4;
    bool on[4];
#pragma unroll
    for (int r = 0; r < 4; ++r)
        on[r] = (orow0 + r < N_NODES) && (cnt[orow0 + r] > 0);

#pragma unroll
    for (int ct = 0; ct < 8; ++ct) {
        const int m = ct * 16 + lr;
        const float bm = b1[m];
#pragma unroll
        for (int r = 0; r < 4; ++r) {
            const int n = orow0 + r;
            if (n < N_NODES) {
                float v = on[r] ? fmaxf(acc[ct][r] + bm, 0.f) : 0.f;
                h1b[(size_t)n * HID_DIM + m] = f2bf(v);
            }
        }
    }
}

// ---------------------------------------------------------------------------
// K3: layer-2 aggregation (128-dim) over ELL; 16 lanes/node, 8-edge pipeline.
// ---------------------------------------------------------------------------
__global__ __launch_bounds__(256) void k_agg2(const unsigned short* __restrict__ Xb,
                                              const int* __restrict__ ell,
                                              const int* __restrict__ cnt,
                                              unsigned short* __restrict__ Mb) {
    const int gid  = threadIdx.x >> 4;
    const int lane = threadIdx.x & 15;
    const int node = blockIdx.x * 16 + gid;     // grid 3125*16 = 50000 exact
    const int c = min(cnt[node], ELLW);
    const float r = (c > 0) ? 1.0f / (float)c : 0.0f;
    const int* er = ell + (size_t)node * ELLW;
    const unsigned short* base = Xb + lane * 8;

    float a0[8], a1[8];
#pragma unroll
    for (int v = 0; v < 8; ++v) { a0[v] = 0.f; a1[v] = 0.f; }

    int j = 0;
    for (; j + 8 <= c; j += 8) {
        const int4 e03 = *reinterpret_cast<const int4*>(er + j);
        const int4 e47 = *reinterpret_cast<const int4*>(er + j + 4);
        uint4 u0 = *reinterpret_cast<const uint4*>(base + (size_t)e03.x * HID_DIM);
        uint4 u1 = *reinterpret_cast<const uint4*>(base + (size_t)e03.y * HID_DIM);
        uint4 u2 = *reinterpret_cast<const uint4*>(base + (size_t)e03.z * HID_DIM);
        uint4 u3 = *reinterpret_cast<const uint4*>(base + (size_t)e03.w * HID_DIM);
        uint4 u4 = *reinterpret_cast<const uint4*>(base + (size_t)e47.x * HID_DIM);
        uint4 u5 = *reinterpret_cast<const uint4*>(base + (size_t)e47.y * HID_DIM);
        uint4 u6 = *reinterpret_cast<const uint4*>(base + (size_t)e47.z * HID_DIM);
        uint4 u7 = *reinterpret_cast<const uint4*>(base + (size_t)e47.w * HID_DIM);
        acc_u4(a0, u0); acc_u4(a1, u1); acc_u4(a0, u2); acc_u4(a1, u3);
        acc_u4(a0, u4); acc_u4(a1, u5); acc_u4(a0, u6); acc_u4(a1, u7);
    }
    for (; j + 4 <= c; j += 4) {
        const int4 e4 = *reinterpret_cast<const int4*>(er + j);
        uint4 u0 = *reinterpret_cast<const uint4*>(base + (size_t)e4.x * HID_DIM);
        uint4 u1 = *reinterpret_cast<const uint4*>(base + (size_t)e4.y * HID_DIM);
        uint4 u2 = *reinterpret_cast<const uint4*>(base + (size_t)e4.z * HID_DIM);
        uint4 u3 = *reinterpret_cast<const uint4*>(base + (size_t)e4.w * HID_DIM);
        acc_u4(a0, u0); acc_u4(a1, u1); acc_u4(a0, u2); acc_u4(a1, u3);
    }
    for (; j < c; ++j) {
        uint4 u = *reinterpret_cast<const uint4*>(base + (size_t)er[j] * HID_DIM);
        acc_u4(a0, u);
    }

    uint4 o;
    o.x = pack2((a0[0] + a1[0]) * r, (a0[1] + a1[1]) * r);
    o.y = pack2((a0[2] + a1[2]) * r, (a0[3] + a1[3]) * r);
    o.z = pack2((a0[4] + a1[4]) * r, (a0[5] + a1[5]) * r);
    o.w = pack2((a0[6] + a1[6]) * r, (a0[7] + a1[7]) * r);
    *reinterpret_cast<uint4*>(Mb + (size_t)node * HID_DIM + lane * 8) = o;
}

// ---------------------------------------------------------------------------
// K4: fused layer-2 GEMM + output GEMM.
//     Phase 1: h2 = relu(m2b @ wp2 + b2) masked -> LDS (bf16, stride 136)
//     Phase 2: out = h2 @ wpo + bout (fp32)
// ---------------------------------------------------------------------------
#define H2S (HID_DIM + 8)
__global__ __launch_bounds__(256) void k_mgemm23(const unsigned short* __restrict__ A,
                                                 const unsigned short* __restrict__ Wp2g,
                                                 const unsigned short* __restrict__ Wpog,
                                                 const float* __restrict__ b2,
                                                 const float* __restrict__ bout,
                                                 const int* __restrict__ cnt,
                                                 float* __restrict__ out) {
    __shared__ unsigned short Wp2s[HID_DIM * HID_DIM];   // 32 KB
    __shared__ unsigned short Wpos[HID_DIM * OUT_DIM];   //  8 KB
    __shared__ unsigned short h2s[64 * H2S];             // 17 KB
    const int tid = threadIdx.x;
#pragma unroll
    for (int f = tid; f < HID_DIM * HID_DIM / 8; f += 256)
        reinterpret_cast<uint4*>(Wp2s)[f] = reinterpret_cast<const uint4*>(Wp2g)[f];
#pragma unroll
    for (int f = tid; f < HID_DIM * OUT_DIM / 8; f += 256)
        reinterpret_cast<uint4*>(Wpos)[f] = reinterpret_cast<const uint4*>(Wpog)[f];
    __syncthreads();

    const int w  = tid >> 6;
    const int l  = tid & 63;
    const int lr = l & 15;
    const int lg = l >> 4;
    const int row = blockIdx.x * 64 + w * 16 + lr;
    const bool rok = row < N_NODES;
    const unsigned short* Arow = A + (size_t)row * HID_DIM;

    fx4_t acc[8];
#pragma unroll
    for (int ct = 0; ct < 8; ++ct) acc[ct] = (fx4_t){0.f, 0.f, 0.f, 0.f};

#pragma unroll
    for (int kc = 0; kc < HID_DIM; kc += 32) {
        bh8_t af = {};
        if (rok) af = *reinterpret_cast<const bh8_t*>(Arow + kc + lg * 8);
#pragma unroll
        for (int ct = 0; ct < 8; ++ct) {
            const bh8_t bf = *reinterpret_cast<const bh8_t*>(
                &Wp2s[(((kc >> 3) + lg) * HID_DIM + ct * 16 + lr) * 8]);
            acc[ct] = __builtin_amdgcn_mfma_f32_16x16x32_bf16(af, bf, acc[ct], 0, 0, 0);
        }
    }

    const int lrow0 = w * 16 + lg * 4;
    const int orow0 = blockIdx.x * 64 + lrow0;
    bool on[4];
#pragma unroll
    for (int r = 0; r < 4; ++r)
        on[r] = (orow0 + r < N_NODES) && (cnt[orow0 + r] > 0);

#pragma unroll
    for (int ct = 0; ct < 8; ++ct) {
        const int m = ct * 16 + lr;
        const float bm = b2[m];
#pragma unroll
        for (int r = 0; r < 4; ++r) {
            float v = on[r] ? fmaxf(acc[ct][r] + bm, 0.f) : 0.f;
            h2s[(lrow0 + r) * H2S + m] = f2bf(v);
        }
    }
    __syncthreads();

    fx4_t acc2[2];
#pragma unroll
    for (int ct = 0; ct < 2; ++ct) acc2[ct] = (fx4_t){0.f, 0.f, 0.f, 0.f};

#pragma unroll
    for (int kc = 0; kc < HID_DIM; kc += 32) {
        const bh8_t af = *reinterpret_cast<const bh8_t*>(
            &h2s[(w * 16 + lr) * H2S + kc + lg * 8]);
#pragma unroll
        for (int ct = 0; ct < 2; ++ct) {
            const bh8_t bf = *reinterpret_cast<const bh8_t*>(
                &Wpos[(((kc >> 3) + lg) * OUT_DIM + ct * 16 + lr) * 8]);
            acc2[ct] = __builtin_amdgcn_mfma_f32_16x16x32_bf16(af, bf, acc2[ct], 0, 0, 0);
        }
    }

#pragma unroll
    for (int ct = 0; ct < 2; ++ct) {
        const int m = ct * 16 + lr;
        const float bm = bout[m];
#pragma unroll
        for (int r = 0; r < 4; ++r) {
            const int n = orow0 + r;
            if (n < N_NODES)
                out[(size_t)n * OUT_DIM + m] = acc2[ct][r] + bm;
        }
    }
}

// ---------------------------------------------------------------------------
extern "C" void kernel_launch(void* const* d_in, const int* in_sizes, int n_in,
                              void* d_out, int out_size, void* d_ws, size_t ws_size,
                              hipStream_t stream) {
    const float* x    = (const float*)d_in[0];
    const int*   ei   = (const int*)d_in[1];
    const float* W1   = (const float*)d_in[2];
    const float* b1   = (const float*)d_in[3];
    const float* W2   = (const float*)d_in[4];
    const float* b2   = (const float*)d_in[5];
    const float* Wout = (const float*)d_in[6];
    const float* bout = (const float*)d_in[7];
    float* out = (float*)d_out;

    const int* src = ei;
    const int* dst = ei + N_EDGES;

    // workspace layout (16B aligned)
    char* ws = (char*)d_ws;
    int*            cnt  = (int*)(ws + 0);                   //    200,000
    int*            bcnt = (int*)(ws + 200000);              //        256
    int2*           bins = (int2*)(ws + 200960);             //  6,912,000 -> 7,112,960
    int*            ell  = (int*)(ws + 7112960);             // 12,800,000 -> 19,912,960
    unsigned short* xb   = (unsigned short*)(ws + 19912960); //  6,400,000 -> 26,312,960
    unsigned short* h1b  = (unsigned short*)(ws + 26312960); // 12,800,000 -> 39,112,960
    unsigned short* m2b  = (unsigned short*)(ws + 39112960); // 12,800,000 -> 51,912,960
    unsigned short* m1b  = (unsigned short*)(ws + 51912960); //  6,400,000 -> 58,312,960
    unsigned short* wp1  = (unsigned short*)(ws + 58312960); //    16,384 -> 58,329,344
    unsigned short* wp2  = (unsigned short*)(ws + 58329344); //    32,768 -> 58,362,112
    unsigned short* wpo  = (unsigned short*)(ws + 58362112); //     8,192 -> 58,370,304

    const int GB = (N_NODES + 63) / 64;          // 782
    const int AB = N_NODES / 16;                 // 3125

    // zero cnt + bcnt in one memset (contiguous)
    hipMemsetAsync(ws, 0, 200960, stream);

    // fused edge binning + prep (cast + weight packing)
    k_bin<<<BIN_BLKS + PREP_BLKS, 256, 0, stream>>>(src, dst, bcnt, bins,
                                                    x, xb, W1, wp1, W2, wp2, Wout, wpo);

    // ELL build from bins (XCD-affine, temporally clustered writes)
    k_ellb<<<ELLB_BLKS, 256, 0, stream>>>(bins, bcnt, cnt, ell);

    // layer 1: aggregate then GEMM
    k_agg1<<<AB, 256, 0, stream>>>(xb, ell, cnt, m1b);
    k_mgemm1<<<GB, 256, 0, stream>>>(m1b, wp1, b1, cnt, h1b);

    // layer 2 aggregation
    k_agg2<<<AB, 256, 0, stream>>>(h1b, ell, cnt, m2b);

    // fused layer-2 GEMM + output GEMM
    k_mgemm23<<<GB, 256, 0, stream>>>(m2b, wp2, wpo, b2, bout, cnt, out);
}

// Round 13
// 166.314 us; speedup vs baseline: 13.3349x; 13.3349x over previous
//
#include <hip/hip_runtime.h>
#include <hip/hip_bf16.h>

#define N_NODES 50000
#define N_EDGES 800000
#define IN_DIM  64
#define HID_DIM 128
#define OUT_DIM 32
#define ELLW    64    // max supported degree; P(max_deg>64) ~ 1e-13 for this graph

#define NBKT   8                       // dst buckets (node ranges of 6250)
#define NWG    8                       // writer groups (XCD-private append)
#define RNG    (N_NODES / NBKT)        // 6250
#define SBCAP  13500                   // sub-bucket capacity: mean 12500, ~9 sigma slack

#define BIN_BLKS  3125   // 800000 edges / 256 (1 edge/thread)
#define CAST_BLKS 3125   // 800000 float4 / 256
#define PW1_BLKS  32     // 64*128/256
#define PW2_BLKS  64     // 128*128/256
#define PWO_BLKS  16     // 128*32/256
#define PREP_BLKS (CAST_BLKS + PW1_BLKS + PW2_BLKS + PWO_BLKS)   // 3237
#define ELLB_BLKS 1024   // 8 buckets x 8 groups x 16 slices

typedef short bh8_t  __attribute__((ext_vector_type(8)));   // 8 bf16 (4 VGPRs)
typedef float fx4_t  __attribute__((ext_vector_type(4)));   // MFMA acc

// bf16 helpers (raw-bit, header-version independent)
__device__ inline float bflo(unsigned int u) {
    union { unsigned int i; float f; } c; c.i = u << 16; return c.f;
}
__device__ inline float bfhi(unsigned int u) {
    union { unsigned int i; float f; } c; c.i = u & 0xffff0000u; return c.f;
}
__device__ inline unsigned short f2bf(float f) {   // round-to-nearest-even
    union { float f; unsigned int i; } c; c.f = f;
    unsigned int u = c.i;
    u += 0x7fffu + ((u >> 16) & 1u);
    return (unsigned short)(u >> 16);
}
__device__ inline unsigned int pack2(float a, float b) {
    return (unsigned int)f2bf(a) | ((unsigned int)f2bf(b) << 16);
}
__device__ inline void acc_u2(float* a, uint2 u) {
    a[0] += bflo(u.x); a[1] += bfhi(u.x);
    a[2] += bflo(u.y); a[3] += bfhi(u.y);
}
__device__ inline void acc_u4(float* a, uint4 u) {
    a[0] += bflo(u.x); a[1] += bfhi(u.x);
    a[2] += bflo(u.y); a[3] += bfhi(u.y);
    a[4] += bflo(u.z); a[5] += bfhi(u.z);
    a[6] += bflo(u.w); a[7] += bfhi(u.w);
}

template <int K, int M>
__device__ inline void packw_one(const float* __restrict__ W,
                                 unsigned short* __restrict__ Wp, int f) {
    const int k = f / M, m = f % M;
    Wp[((k >> 3) * M + m) * 8 + (k & 7)] = f2bf(W[f]);
}

// ---------------------------------------------------------------------------
// K0: fused edge-binning + prep.  bcnt zeroed beforehand.
//     Binning blocks: LDS-aggregated reservation — count the block's 256
//     edges per bucket in LDS, reserve ranges with ONE global atomicAdd per
//     (bucket, block) [25k atomics over 64 counters vs round-12's 800k ->
//     kills the contention that made k_bin 2.1ms], then write each edge to
//     its reserved slot.  Appends stay dense + XCD-private (g = bid&7).
//     Blocks [BIN_BLKS, +PREP_BLKS): cast x->bf16, pack W1/W2/Wout.
// ---------------------------------------------------------------------------
__global__ __launch_bounds__(256) void k_bin(const int* __restrict__ src,
                                             const int* __restrict__ dst,
                                             int* __restrict__ bcnt,
                                             int2* __restrict__ bins,
                                             const float* __restrict__ x,
                                             unsigned short* __restrict__ xb,
                                             const float* __restrict__ W1,
                                             unsigned short* __restrict__ wp1,
                                             const float* __restrict__ W2,
                                             unsigned short* __restrict__ wp2,
                                             const float* __restrict__ Wout,
                                             unsigned short* __restrict__ wpo) {
    __shared__ int lcnt[NBKT];
    __shared__ int lbase[NBKT];
    const int bid = blockIdx.x;
    if (bid < BIN_BLKS) {
        const int g = bid & (NWG - 1);
        const int e = bid * 256 + threadIdx.x;   // 3125*256 = 800000 exact
        const int d = dst[e];
        const int s = src[e];
        const int b = d / RNG;
        if (threadIdx.x < NBKT) lcnt[threadIdx.x] = 0;
        __syncthreads();
        const int rank = atomicAdd(&lcnt[b], 1);
        __syncthreads();
        if (threadIdx.x < NBKT) {
            const int c = lcnt[threadIdx.x];
            lbase[threadIdx.x] =
                (c > 0) ? atomicAdd(&bcnt[threadIdx.x * NWG + g], c) : 0;
        }
        __syncthreads();
        const int p = lbase[b] + rank;
        if (p < SBCAP) bins[(size_t)(b * NWG + g) * SBCAP + p] = make_int2(s, d);
        return;
    }
    const int pb = bid - BIN_BLKS;
    if (pb < CAST_BLKS) {
        const int i = pb * 256 + threadIdx.x;    // exactly 800000 float4s
        float4 v = reinterpret_cast<const float4*>(x)[i];
        ushort4 o;
        o.x = f2bf(v.x); o.y = f2bf(v.y); o.z = f2bf(v.z); o.w = f2bf(v.w);
        reinterpret_cast<ushort4*>(xb)[i] = o;
    } else if (pb < CAST_BLKS + PW1_BLKS) {
        packw_one<IN_DIM, HID_DIM>(W1, wp1, (pb - CAST_BLKS) * 256 + threadIdx.x);
    } else if (pb < CAST_BLKS + PW1_BLKS + PW2_BLKS) {
        packw_one<HID_DIM, HID_DIM>(W2, wp2, (pb - CAST_BLKS - PW1_BLKS) * 256 + threadIdx.x);
    } else {
        packw_one<HID_DIM, OUT_DIM>(Wout, wpo,
                                    (pb - CAST_BLKS - PW1_BLKS - PW2_BLKS) * 256 + threadIdx.x);
    }
}

// ---------------------------------------------------------------------------
// K0b: ELL build from bins.  Bucket b is processed ONLY by blocks with
//      bid&7 == b (one XCD), all within one short window -> each node's
//      256B ELL row accumulates its ~16 writes while the bucket's 1.6MB
//      footprint is L2-resident.  cnt atomics are XCD-local too.
// ---------------------------------------------------------------------------
__global__ __launch_bounds__(256) void k_ellb(const int2* __restrict__ bins,
                                              const int* __restrict__ bcnt,
                                              int* __restrict__ cnt,
                                              int* __restrict__ ell) {
    const int b = blockIdx.x & (NBKT - 1);
    const int g = (blockIdx.x >> 3) & (NWG - 1);
    const int j = blockIdx.x >> 6;              // 0..15
    const int sb = b * NWG + g;
    const int cg = min(bcnt[sb], SBCAP);
    const int2* bb = bins + (size_t)sb * SBCAP;
    for (int i = j * 256 + threadIdx.x; i < cg; i += 16 * 256) {
        const int2 e = bb[i];
        const int p = atomicAdd(&cnt[e.y], 1);
        if (p < ELLW) ell[(size_t)e.y * ELLW + p] = e.x;
    }
}

// ---------------------------------------------------------------------------
// K1: layer-1 aggregation (64-dim) over ELL; 16 lanes/node, 8-edge pipeline.
//     m1b = bf16(mean of neighbor xb rows), fp32 acc.
// ---------------------------------------------------------------------------
__global__ __launch_bounds__(256) void k_agg1(const unsigned short* __restrict__ Xb,
                                              const int* __restrict__ ell,
                                              const int* __restrict__ cnt,
                                              unsigned short* __restrict__ Mb) {
    const int gid  = threadIdx.x >> 4;
    const int lane = threadIdx.x & 15;
    const int node = blockIdx.x * 16 + gid;     // grid 3125*16 = 50000 exact
    const int c = min(cnt[node], ELLW);
    const float r = (c > 0) ? 1.0f / (float)c : 0.0f;
    const int* er = ell + (size_t)node * ELLW;
    const unsigned short* base = Xb + lane * 4;

    float a0[4], a1[4];
#pragma unroll
    for (int v = 0; v < 4; ++v) { a0[v] = 0.f; a1[v] = 0.f; }

    int j = 0;
    for (; j + 8 <= c; j += 8) {
        const int4 e03 = *reinterpret_cast<const int4*>(er + j);
        const int4 e47 = *reinterpret_cast<const int4*>(er + j + 4);
        uint2 u0 = *reinterpret_cast<const uint2*>(base + (size_t)e03.x * IN_DIM);
        uint2 u1 = *reinterpret_cast<const uint2*>(base + (size_t)e03.y * IN_DIM);
        uint2 u2 = *reinterpret_cast<const uint2*>(base + (size_t)e03.z * IN_DIM);
        uint2 u3 = *reinterpret_cast<const uint2*>(base + (size_t)e03.w * IN_DIM);
        uint2 u4 = *reinterpret_cast<const uint2*>(base + (size_t)e47.x * IN_DIM);
        uint2 u5 = *reinterpret_cast<const uint2*>(base + (size_t)e47.y * IN_DIM);
        uint2 u6 = *reinterpret_cast<const uint2*>(base + (size_t)e47.z * IN_DIM);
        uint2 u7 = *reinterpret_cast<const uint2*>(base + (size_t)e47.w * IN_DIM);
        acc_u2(a0, u0); acc_u2(a1, u1); acc_u2(a0, u2); acc_u2(a1, u3);
        acc_u2(a0, u4); acc_u2(a1, u5); acc_u2(a0, u6); acc_u2(a1, u7);
    }
    for (; j + 4 <= c; j += 4) {
        const int4 e4 = *reinterpret_cast<const int4*>(er + j);
        uint2 u0 = *reinterpret_cast<const uint2*>(base + (size_t)e4.x * IN_DIM);
        uint2 u1 = *reinterpret_cast<const uint2*>(base + (size_t)e4.y * IN_DIM);
        uint2 u2 = *reinterpret_cast<const uint2*>(base + (size_t)e4.z * IN_DIM);
        uint2 u3 = *reinterpret_cast<const uint2*>(base + (size_t)e4.w * IN_DIM);
        acc_u2(a0, u0); acc_u2(a1, u1); acc_u2(a0, u2); acc_u2(a1, u3);
    }
    for (; j < c; ++j) {
        uint2 u = *reinterpret_cast<const uint2*>(base + (size_t)er[j] * IN_DIM);
        acc_u2(a0, u);
    }

    uint2 o;
    o.x = pack2((a0[0] + a1[0]) * r, (a0[1] + a1[1]) * r);
    o.y = pack2((a0[2] + a1[2]) * r, (a0[3] + a1[3]) * r);
    *reinterpret_cast<uint2*>(Mb + (size_t)node * IN_DIM + lane * 4) = o;
}

// ---------------------------------------------------------------------------
// K2: layer-1 MFMA GEMM.  h1b = bf16(relu(m1b @ wp1 + b1)), masked by cnt.
// ---------------------------------------------------------------------------
__global__ __launch_bounds__(256) void k_mgemm1(const unsigned short* __restrict__ A,
                                                const unsigned short* __restrict__ Wpg,
                                                const float* __restrict__ b1,
                                                const int* __restrict__ cnt,
                                                unsigned short* __restrict__ h1b) {
    __shared__ unsigned short Wp[IN_DIM * HID_DIM];   // 16 KB
    const int tid = threadIdx.x;
#pragma unroll
    for (int f = tid; f < IN_DIM * HID_DIM / 8; f += 256)
        reinterpret_cast<uint4*>(Wp)[f] = reinterpret_cast<const uint4*>(Wpg)[f];
    __syncthreads();

    const int w  = tid >> 6;
    const int l  = tid & 63;
    const int lr = l & 15;
    const int lg = l >> 4;
    const int row = blockIdx.x * 64 + w * 16 + lr;
    const bool rok = row < N_NODES;
    const unsigned short* Arow = A + (size_t)row * IN_DIM;

    fx4_t acc[8];
#pragma unroll
    for (int ct = 0; ct < 8; ++ct) acc[ct] = (fx4_t){0.f, 0.f, 0.f, 0.f};

#pragma unroll
    for (int kc = 0; kc < IN_DIM; kc += 32) {
        bh8_t af = {};
        if (rok) af = *reinterpret_cast<const bh8_t*>(Arow + kc + lg * 8);
#pragma unroll
        for (int ct = 0; ct < 8; ++ct) {
            const bh8_t bf = *reinterpret_cast<const bh8_t*>(
                &Wp[(((kc >> 3) + lg) * HID_DIM + ct * 16 + lr) * 8]);
            acc[ct] = __builtin_amdgcn_mfma_f32_16x16x32_bf16(af, bf, acc[ct], 0, 0, 0);
        }
    }

    const int orow0 = blockIdx.x * 64 + w * 16 + lg * 4;
    bool on[4];
#pragma unroll
    for (int r = 0; r < 4; ++r)
        on[r] = (orow0 + r < N_NODES) && (cnt[orow0 + r] > 0);

#pragma unroll
    for (int ct = 0; ct < 8; ++ct) {
        const int m = ct * 16 + lr;
        const float bm = b1[m];
#pragma unroll
        for (int r = 0; r < 4; ++r) {
            const int n = orow0 + r;
            if (n < N_NODES) {
                float v = on[r] ? fmaxf(acc[ct][r] + bm, 0.f) : 0.f;
                h1b[(size_t)n * HID_DIM + m] = f2bf(v);
            }
        }
    }
}

// ---------------------------------------------------------------------------
// K3: layer-2 aggregation (128-dim) over ELL; 16 lanes/node, 8-edge pipeline.
// ---------------------------------------------------------------------------
__global__ __launch_bounds__(256) void k_agg2(const unsigned short* __restrict__ Xb,
                                              const int* __restrict__ ell,
                                              const int* __restrict__ cnt,
                                              unsigned short* __restrict__ Mb) {
    const int gid  = threadIdx.x >> 4;
    const int lane = threadIdx.x & 15;
    const int node = blockIdx.x * 16 + gid;     // grid 3125*16 = 50000 exact
    const int c = min(cnt[node], ELLW);
    const float r = (c > 0) ? 1.0f / (float)c : 0.0f;
    const int* er = ell + (size_t)node * ELLW;
    const unsigned short* base = Xb + lane * 8;

    float a0[8], a1[8];
#pragma unroll
    for (int v = 0; v < 8; ++v) { a0[v] = 0.f; a1[v] = 0.f; }

    int j = 0;
    for (; j + 8 <= c; j += 8) {
        const int4 e03 = *reinterpret_cast<const int4*>(er + j);
        const int4 e47 = *reinterpret_cast<const int4*>(er + j + 4);
        uint4 u0 = *reinterpret_cast<const uint4*>(base + (size_t)e03.x * HID_DIM);
        uint4 u1 = *reinterpret_cast<const uint4*>(base + (size_t)e03.y * HID_DIM);
        uint4 u2 = *reinterpret_cast<const uint4*>(base + (size_t)e03.z * HID_DIM);
        uint4 u3 = *reinterpret_cast<const uint4*>(base + (size_t)e03.w * HID_DIM);
        uint4 u4 = *reinterpret_cast<const uint4*>(base + (size_t)e47.x * HID_DIM);
        uint4 u5 = *reinterpret_cast<const uint4*>(base + (size_t)e47.y * HID_DIM);
        uint4 u6 = *reinterpret_cast<const uint4*>(base + (size_t)e47.z * HID_DIM);
        uint4 u7 = *reinterpret_cast<const uint4*>(base + (size_t)e47.w * HID_DIM);
        acc_u4(a0, u0); acc_u4(a1, u1); acc_u4(a0, u2); acc_u4(a1, u3);
        acc_u4(a0, u4); acc_u4(a1, u5); acc_u4(a0, u6); acc_u4(a1, u7);
    }
    for (; j + 4 <= c; j += 4) {
        const int4 e4 = *reinterpret_cast<const int4*>(er + j);
        uint4 u0 = *reinterpret_cast<const uint4*>(base + (size_t)e4.x * HID_DIM);
        uint4 u1 = *reinterpret_cast<const uint4*>(base + (size_t)e4.y * HID_DIM);
        uint4 u2 = *reinterpret_cast<const uint4*>(base + (size_t)e4.z * HID_DIM);
        uint4 u3 = *reinterpret_cast<const uint4*>(base + (size_t)e4.w * HID_DIM);
        acc_u4(a0, u0); acc_u4(a1, u1); acc_u4(a0, u2); acc_u4(a1, u3);
    }
    for (; j < c; ++j) {
        uint4 u = *reinterpret_cast<const uint4*>(base + (size_t)er[j] * HID_DIM);
        acc_u4(a0, u);
    }

    uint4 o;
    o.x = pack2((a0[0] + a1[0]) * r, (a0[1] + a1[1]) * r);
    o.y = pack2((a0[2] + a1[2]) * r, (a0[3] + a1[3]) * r);
    o.z = pack2((a0[4] + a1[4]) * r, (a0[5] + a1[5]) * r);
    o.w = pack2((a0[6] + a1[6]) * r, (a0[7] + a1[7]) * r);
    *reinterpret_cast<uint4*>(Mb + (size_t)node * HID_DIM + lane * 8) = o;
}

// ---------------------------------------------------------------------------
// K4: fused layer-2 GEMM + output GEMM.
//     Phase 1: h2 = relu(m2b @ wp2 + b2) masked -> LDS (bf16, stride 136)
//     Phase 2: out = h2 @ wpo + bout (fp32)
// ---------------------------------------------------------------------------
#define H2S (HID_DIM + 8)
__global__ __launch_bounds__(256) void k_mgemm23(const unsigned short* __restrict__ A,
                                                 const unsigned short* __restrict__ Wp2g,
                                                 const unsigned short* __restrict__ Wpog,
                                                 const float* __restrict__ b2,
                                                 const float* __restrict__ bout,
                                                 const int* __restrict__ cnt,
                                                 float* __restrict__ out) {
    __shared__ unsigned short Wp2s[HID_DIM * HID_DIM];   // 32 KB
    __shared__ unsigned short Wpos[HID_DIM * OUT_DIM];   //  8 KB
    __shared__ unsigned short h2s[64 * H2S];             // 17 KB
    const int tid = threadIdx.x;
#pragma unroll
    for (int f = tid; f < HID_DIM * HID_DIM / 8; f += 256)
        reinterpret_cast<uint4*>(Wp2s)[f] = reinterpret_cast<const uint4*>(Wp2g)[f];
#pragma unroll
    for (int f = tid; f < HID_DIM * OUT_DIM / 8; f += 256)
        reinterpret_cast<uint4*>(Wpos)[f] = reinterpret_cast<const uint4*>(Wpog)[f];
    __syncthreads();

    const int w  = tid >> 6;
    const int l  = tid & 63;
    const int lr = l & 15;
    const int lg = l >> 4;
    const int row = blockIdx.x * 64 + w * 16 + lr;
    const bool rok = row < N_NODES;
    const unsigned short* Arow = A + (size_t)row * HID_DIM;

    fx4_t acc[8];
#pragma unroll
    for (int ct = 0; ct < 8; ++ct) acc[ct] = (fx4_t){0.f, 0.f, 0.f, 0.f};

#pragma unroll
    for (int kc = 0; kc < HID_DIM; kc += 32) {
        bh8_t af = {};
        if (rok) af = *reinterpret_cast<const bh8_t*>(Arow + kc + lg * 8);
#pragma unroll
        for (int ct = 0; ct < 8; ++ct) {
            const bh8_t bf = *reinterpret_cast<const bh8_t*>(
                &Wp2s[(((kc >> 3) + lg) * HID_DIM + ct * 16 + lr) * 8]);
            acc[ct] = __builtin_amdgcn_mfma_f32_16x16x32_bf16(af, bf, acc[ct], 0, 0, 0);
        }
    }

    const int lrow0 = w * 16 + lg * 4;
    const int orow0 = blockIdx.x * 64 + lrow0;
    bool on[4];
#pragma unroll
    for (int r = 0; r < 4; ++r)
        on[r] = (orow0 + r < N_NODES) && (cnt[orow0 + r] > 0);

#pragma unroll
    for (int ct = 0; ct < 8; ++ct) {
        const int m = ct * 16 + lr;
        const float bm = b2[m];
#pragma unroll
        for (int r = 0; r < 4; ++r) {
            float v = on[r] ? fmaxf(acc[ct][r] + bm, 0.f) : 0.f;
            h2s[(lrow0 + r) * H2S + m] = f2bf(v);
        }
    }
    __syncthreads();

    fx4_t acc2[2];
#pragma unroll
    for (int ct = 0; ct < 2; ++ct) acc2[ct] = (fx4_t){0.f, 0.f, 0.f, 0.f};

#pragma unroll
    for (int kc = 0; kc < HID_DIM; kc += 32) {
        const bh8_t af = *reinterpret_cast<const bh8_t*>(
            &h2s[(w * 16 + lr) * H2S + kc + lg * 8]);
#pragma unroll
        for (int ct = 0; ct < 2; ++ct) {
            const bh8_t bf = *reinterpret_cast<const bh8_t*>(
                &Wpos[(((kc >> 3) + lg) * OUT_DIM + ct * 16 + lr) * 8]);
            acc2[ct] = __builtin_amdgcn_mfma_f32_16x16x32_bf16(af, bf, acc2[ct], 0, 0, 0);
        }
    }

#pragma unroll
    for (int ct = 0; ct < 2; ++ct) {
        const int m = ct * 16 + lr;
        const float bm = bout[m];
#pragma unroll
        for (int r = 0; r < 4; ++r) {
            const int n = orow0 + r;
            if (n < N_NODES)
                out[(size_t)n * OUT_DIM + m] = acc2[ct][r] + bm;
        }
    }
}

// ---------------------------------------------------------------------------
extern "C" void kernel_launch(void* const* d_in, const int* in_sizes, int n_in,
                              void* d_out, int out_size, void* d_ws, size_t ws_size,
                              hipStream_t stream) {
    const float* x    = (const float*)d_in[0];
    const int*   ei   = (const int*)d_in[1];
    const float* W1   = (const float*)d_in[2];
    const float* b1   = (const float*)d_in[3];
    const float* W2   = (const float*)d_in[4];
    const float* b2   = (const float*)d_in[5];
    const float* Wout = (const float*)d_in[6];
    const float* bout = (const float*)d_in[7];
    float* out = (float*)d_out;

    const int* src = ei;
    const int* dst = ei + N_EDGES;

    // workspace layout (16B aligned)
    char* ws = (char*)d_ws;
    int*            cnt  = (int*)(ws + 0);                   //    200,000
    int*            bcnt = (int*)(ws + 200000);              //        256
    int2*           bins = (int2*)(ws + 200960);             //  6,912,000 -> 7,112,960
    int*            ell  = (int*)(ws + 7112960);             // 12,800,000 -> 19,912,960
    unsigned short* xb   = (unsigned short*)(ws + 19912960); //  6,400,000 -> 26,312,960
    unsigned short* h1b  = (unsigned short*)(ws + 26312960); // 12,800,000 -> 39,112,960
    unsigned short* m2b  = (unsigned short*)(ws + 39112960); // 12,800,000 -> 51,912,960
    unsigned short* m1b  = (unsigned short*)(ws + 51912960); //  6,400,000 -> 58,312,960
    unsigned short* wp1  = (unsigned short*)(ws + 58312960); //    16,384 -> 58,329,344
    unsigned short* wp2  = (unsigned short*)(ws + 58329344); //    32,768 -> 58,362,112
    unsigned short* wpo  = (unsigned short*)(ws + 58362112); //     8,192 -> 58,370,304

    const int GB = (N_NODES + 63) / 64;          // 782
    const int AB = N_NODES / 16;                 // 3125

    // zero cnt + bcnt in one memset (contiguous)
    hipMemsetAsync(ws, 0, 200960, stream);

    // fused edge binning (LDS-aggregated reservation) + prep
    k_bin<<<BIN_BLKS + PREP_BLKS, 256, 0, stream>>>(src, dst, bcnt, bins,
                                                    x, xb, W1, wp1, W2, wp2, Wout, wpo);

    // ELL build from bins (XCD-affine, temporally clustered writes)
    k_ellb<<<ELLB_BLKS, 256, 0, stream>>>(bins, bcnt, cnt, ell);

    // layer 1: aggregate then GEMM
    k_agg1<<<AB, 256, 0, stream>>>(xb, ell, cnt, m1b);
    k_mgemm1<<<GB, 256, 0, stream>>>(m1b, wp1, b1, cnt, h1b);

    // layer 2 aggregation
    k_agg2<<<AB, 256, 0, stream>>>(h1b, ell, cnt, m2b);

    // fused layer-2 GEMM + output GEMM
    k_mgemm23<<<GB, 256, 0, stream>>>(m2b, wp2, wpo, b2, bout, cnt, out);
}

// Round 14
// 130.885 us; speedup vs baseline: 16.9446x; 1.2707x over previous
//
#include <hip/hip_runtime.h>
#include <hip/hip_bf16.h>

#define N_NODES 50000
#define N_EDGES 800000
#define IN_DIM  64
#define HID_DIM 128
#define OUT_DIM 32
#define ELLW    64    // max supported degree; P(max_deg>64) ~ 1e-13 for this graph

#define NRANGE   8
#define RNG      (N_NODES / NRANGE)                      // 6250
#define FILL_CH  2048
#define FILL_NJ  ((N_EDGES + FILL_CH - 1) / FILL_CH)     // 391

#define CAST_BLKS 3125   // 800000 float4 / 256
#define PW1_BLKS  32     // 64*128/256
#define PW2_BLKS  64     // 128*128/256
#define PWO_BLKS  16     // 128*32/256
#define ZERO_BLKS 49     // 49*1024 >= 50000 ints

typedef short bh8_t  __attribute__((ext_vector_type(8)));   // 8 bf16 (4 VGPRs)
typedef float fx4_t  __attribute__((ext_vector_type(4)));   // MFMA acc

// bf16 helpers (raw-bit, header-version independent)
__device__ inline float bflo(unsigned int u) {
    union { unsigned int i; float f; } c; c.i = u << 16; return c.f;
}
__device__ inline float bfhi(unsigned int u) {
    union { unsigned int i; float f; } c; c.i = u & 0xffff0000u; return c.f;
}
__device__ inline unsigned short f2bf(float f) {   // round-to-nearest-even
    union { float f; unsigned int i; } c; c.f = f;
    unsigned int u = c.i;
    u += 0x7fffu + ((u >> 16) & 1u);
    return (unsigned short)(u >> 16);
}
__device__ inline unsigned int pack2(float a, float b) {
    return (unsigned int)f2bf(a) | ((unsigned int)f2bf(b) << 16);
}
__device__ inline void acc_u2(float* a, uint2 u) {
    a[0] += bflo(u.x); a[1] += bfhi(u.x);
    a[2] += bflo(u.y); a[3] += bfhi(u.y);
}
__device__ inline void acc_u4(float* a, uint4 u) {
    a[0] += bflo(u.x); a[1] += bfhi(u.x);
    a[2] += bflo(u.y); a[3] += bfhi(u.y);
    a[4] += bflo(u.z); a[5] += bfhi(u.z);
    a[6] += bflo(u.w); a[7] += bfhi(u.w);
}

template <int K, int M>
__device__ inline void packw_one(const float* __restrict__ W,
                                 unsigned short* __restrict__ Wp, int f) {
    const int k = f / M, m = f % M;
    Wp[((k >> 3) * M + m) * 8 + (k & 7)] = f2bf(W[f]);
}

// ---------------------------------------------------------------------------
// K0: prep — cast x -> bf16, pack W1/W2/Wout, zero cnt.  Runs BEFORE the
//     scatter (separate kernel): co-scheduling the 19MB cast stream with the
//     scatter evicts the scatter's L2-resident ELL lines (R9's k_pe showed
//     WRITE 37.8MB vs ideal 19MB) — keep them apart.
// ---------------------------------------------------------------------------
__global__ void k_prep(const float* __restrict__ x, unsigned short* __restrict__ xb,
                       const float* __restrict__ W1, unsigned short* __restrict__ wp1,
                       const float* __restrict__ W2, unsigned short* __restrict__ wp2,
                       const float* __restrict__ Wout, unsigned short* __restrict__ wpo,
                       int* __restrict__ cnt) {
    const int bid = blockIdx.x;
    if (bid < CAST_BLKS) {
        const int i = bid * 256 + threadIdx.x;            // exactly 800000 float4s
        float4 v = reinterpret_cast<const float4*>(x)[i];
        ushort4 o;
        o.x = f2bf(v.x); o.y = f2bf(v.y); o.z = f2bf(v.z); o.w = f2bf(v.w);
        reinterpret_cast<ushort4*>(xb)[i] = o;
    } else if (bid < CAST_BLKS + PW1_BLKS) {
        packw_one<IN_DIM, HID_DIM>(W1, wp1, (bid - CAST_BLKS) * 256 + threadIdx.x);
    } else if (bid < CAST_BLKS + PW1_BLKS + PW2_BLKS) {
        packw_one<HID_DIM, HID_DIM>(W2, wp2, (bid - CAST_BLKS - PW1_BLKS) * 256 + threadIdx.x);
    } else if (bid < CAST_BLKS + PW1_BLKS + PW2_BLKS + PWO_BLKS) {
        packw_one<HID_DIM, OUT_DIM>(Wout, wpo,
                                    (bid - CAST_BLKS - PW1_BLKS - PW2_BLKS) * 256 + threadIdx.x);
    } else {
        const int zb = bid - (CAST_BLKS + PW1_BLKS + PW2_BLKS + PWO_BLKS);
#pragma unroll
        for (int k2 = 0; k2 < 4; ++k2) {
            const int i = zb * 1024 + k2 * 256 + threadIdx.x;
            if (i < N_NODES) cnt[i] = 0;
        }
    }
}

// ---------------------------------------------------------------------------
// K1: single-pass ELL build, dst-range x XCD partitioned (round-7 champion
//     version: 2048-edge chunks, 8 iterations/block).  r = blockIdx&7 owns
//     dst range [r*6250,(r+1)*6250) and round-robins to one XCD, so each
//     node's 256B ELL row is written by ONE XCD while its 1.6MB range slice
//     is L2-resident.  8x redundant dst reads (~25MB) are L2/L3-served.
//     [A/B evidence: this beat the 1-edge/thread variant in total time,
//      R7=131.4 vs R8=137.2.]
// ---------------------------------------------------------------------------
__global__ __launch_bounds__(256) void k_ell(const int* __restrict__ src,
                                             const int* __restrict__ dst,
                                             int* __restrict__ cnt,
                                             int* __restrict__ ell) {
    const int r    = blockIdx.x & (NRANGE - 1);
    const int j    = blockIdx.x >> 3;
    const int lo   = r * RNG;
    const int base = j * FILL_CH;
#pragma unroll
    for (int i = 0; i < FILL_CH / 256; ++i) {
        const int e = base + i * 256 + threadIdx.x;
        if (e < N_EDGES) {
            const int d = dst[e];
            if ((unsigned)(d - lo) < (unsigned)RNG) {
                const int p = atomicAdd(&cnt[d], 1);
                if (p < ELLW) ell[(size_t)d * ELLW + p] = src[e];
            }
        }
    }
}

// ---------------------------------------------------------------------------
// K2: layer-1 aggregation (64-dim) over ELL; 16 lanes/node, 8-edge pipeline.
//     m1b = bf16(mean of neighbor xb rows), fp32 acc.  [Split from the GEMM:
//     the fused version (R7/R8 k_ag1, 4 threads/node) was 41µs latency-bound;
//     16 lanes/node restores 4x memory-level parallelism.]
// ---------------------------------------------------------------------------
__global__ __launch_bounds__(256) void k_agg1(const unsigned short* __restrict__ Xb,
                                              const int* __restrict__ ell,
                                              const int* __restrict__ cnt,
                                              unsigned short* __restrict__ Mb) {
    const int gid  = threadIdx.x >> 4;
    const int lane = threadIdx.x & 15;
    const int node = blockIdx.x * 16 + gid;     // grid 3125*16 = 50000 exact
    const int c = min(cnt[node], ELLW);
    const float r = (c > 0) ? 1.0f / (float)c : 0.0f;
    const int* er = ell + (size_t)node * ELLW;
    const unsigned short* base = Xb + lane * 4;

    float a0[4], a1[4];
#pragma unroll
    for (int v = 0; v < 4; ++v) { a0[v] = 0.f; a1[v] = 0.f; }

    int j = 0;
    for (; j + 8 <= c; j += 8) {
        const int4 e03 = *reinterpret_cast<const int4*>(er + j);
        const int4 e47 = *reinterpret_cast<const int4*>(er + j + 4);
        uint2 u0 = *reinterpret_cast<const uint2*>(base + (size_t)e03.x * IN_DIM);
        uint2 u1 = *reinterpret_cast<const uint2*>(base + (size_t)e03.y * IN_DIM);
        uint2 u2 = *reinterpret_cast<const uint2*>(base + (size_t)e03.z * IN_DIM);
        uint2 u3 = *reinterpret_cast<const uint2*>(base + (size_t)e03.w * IN_DIM);
        uint2 u4 = *reinterpret_cast<const uint2*>(base + (size_t)e47.x * IN_DIM);
        uint2 u5 = *reinterpret_cast<const uint2*>(base + (size_t)e47.y * IN_DIM);
        uint2 u6 = *reinterpret_cast<const uint2*>(base + (size_t)e47.z * IN_DIM);
        uint2 u7 = *reinterpret_cast<const uint2*>(base + (size_t)e47.w * IN_DIM);
        acc_u2(a0, u0); acc_u2(a1, u1); acc_u2(a0, u2); acc_u2(a1, u3);
        acc_u2(a0, u4); acc_u2(a1, u5); acc_u2(a0, u6); acc_u2(a1, u7);
    }
    for (; j + 4 <= c; j += 4) {
        const int4 e4 = *reinterpret_cast<const int4*>(er + j);
        uint2 u0 = *reinterpret_cast<const uint2*>(base + (size_t)e4.x * IN_DIM);
        uint2 u1 = *reinterpret_cast<const uint2*>(base + (size_t)e4.y * IN_DIM);
        uint2 u2 = *reinterpret_cast<const uint2*>(base + (size_t)e4.z * IN_DIM);
        uint2 u3 = *reinterpret_cast<const uint2*>(base + (size_t)e4.w * IN_DIM);
        acc_u2(a0, u0); acc_u2(a1, u1); acc_u2(a0, u2); acc_u2(a1, u3);
    }
    for (; j < c; ++j) {
        uint2 u = *reinterpret_cast<const uint2*>(base + (size_t)er[j] * IN_DIM);
        acc_u2(a0, u);
    }

    uint2 o;
    o.x = pack2((a0[0] + a1[0]) * r, (a0[1] + a1[1]) * r);
    o.y = pack2((a0[2] + a1[2]) * r, (a0[3] + a1[3]) * r);
    *reinterpret_cast<uint2*>(Mb + (size_t)node * IN_DIM + lane * 4) = o;
}

// ---------------------------------------------------------------------------
// K3: layer-1 MFMA GEMM.  h1b = bf16(relu(m1b @ wp1 + b1)), masked by cnt.
// ---------------------------------------------------------------------------
__global__ __launch_bounds__(256) void k_mgemm1(const unsigned short* __restrict__ A,
                                                const unsigned short* __restrict__ Wpg,
                                                const float* __restrict__ b1,
                                                const int* __restrict__ cnt,
                                                unsigned short* __restrict__ h1b) {
    __shared__ unsigned short Wp[IN_DIM * HID_DIM];   // 16 KB
    const int tid = threadIdx.x;
#pragma unroll
    for (int f = tid; f < IN_DIM * HID_DIM / 8; f += 256)
        reinterpret_cast<uint4*>(Wp)[f] = reinterpret_cast<const uint4*>(Wpg)[f];
    __syncthreads();

    const int w  = tid >> 6;
    const int l  = tid & 63;
    const int lr = l & 15;
    const int lg = l >> 4;
    const int row = blockIdx.x * 64 + w * 16 + lr;
    const bool rok = row < N_NODES;
    const unsigned short* Arow = A + (size_t)row * IN_DIM;

    fx4_t acc[8];
#pragma unroll
    for (int ct = 0; ct < 8; ++ct) acc[ct] = (fx4_t){0.f, 0.f, 0.f, 0.f};

#pragma unroll
    for (int kc = 0; kc < IN_DIM; kc += 32) {
        bh8_t af = {};
        if (rok) af = *reinterpret_cast<const bh8_t*>(Arow + kc + lg * 8);
#pragma unroll
        for (int ct = 0; ct < 8; ++ct) {
            const bh8_t bf = *reinterpret_cast<const bh8_t*>(
                &Wp[(((kc >> 3) + lg) * HID_DIM + ct * 16 + lr) * 8]);
            acc[ct] = __builtin_amdgcn_mfma_f32_16x16x32_bf16(af, bf, acc[ct], 0, 0, 0);
        }
    }

    const int orow0 = blockIdx.x * 64 + w * 16 + lg * 4;
    bool on[4];
#pragma unroll
    for (int r = 0; r < 4; ++r)
        on[r] = (orow0 + r < N_NODES) && (cnt[orow0 + r] > 0);

#pragma unroll
    for (int ct = 0; ct < 8; ++ct) {
        const int m = ct * 16 + lr;
        const float bm = b1[m];
#pragma unroll
        for (int r = 0; r < 4; ++r) {
            const int n = orow0 + r;
            if (n < N_NODES) {
                float v = on[r] ? fmaxf(acc[ct][r] + bm, 0.f) : 0.f;
                h1b[(size_t)n * HID_DIM + m] = f2bf(v);
            }
        }
    }
}

// ---------------------------------------------------------------------------
// K4: layer-2 aggregation (128-dim) over ELL; 16 lanes/node, 8-edge pipeline.
// ---------------------------------------------------------------------------
__global__ __launch_bounds__(256) void k_agg2(const unsigned short* __restrict__ Xb,
                                              const int* __restrict__ ell,
                                              const int* __restrict__ cnt,
                                              unsigned short* __restrict__ Mb) {
    const int gid  = threadIdx.x >> 4;
    const int lane = threadIdx.x & 15;
    const int node = blockIdx.x * 16 + gid;     // grid 3125*16 = 50000 exact
    const int c = min(cnt[node], ELLW);
    const float r = (c > 0) ? 1.0f / (float)c : 0.0f;
    const int* er = ell + (size_t)node * ELLW;
    const unsigned short* base = Xb + lane * 8;

    float a0[8], a1[8];
#pragma unroll
    for (int v = 0; v < 8; ++v) { a0[v] = 0.f; a1[v] = 0.f; }

    int j = 0;
    for (; j + 8 <= c; j += 8) {
        const int4 e03 = *reinterpret_cast<const int4*>(er + j);
        const int4 e47 = *reinterpret_cast<const int4*>(er + j + 4);
        uint4 u0 = *reinterpret_cast<const uint4*>(base + (size_t)e03.x * HID_DIM);
        uint4 u1 = *reinterpret_cast<const uint4*>(base + (size_t)e03.y * HID_DIM);
        uint4 u2 = *reinterpret_cast<const uint4*>(base + (size_t)e03.z * HID_DIM);
        uint4 u3 = *reinterpret_cast<const uint4*>(base + (size_t)e03.w * HID_DIM);
        uint4 u4 = *reinterpret_cast<const uint4*>(base + (size_t)e47.x * HID_DIM);
        uint4 u5 = *reinterpret_cast<const uint4*>(base + (size_t)e47.y * HID_DIM);
        uint4 u6 = *reinterpret_cast<const uint4*>(base + (size_t)e47.z * HID_DIM);
        uint4 u7 = *reinterpret_cast<const uint4*>(base + (size_t)e47.w * HID_DIM);
        acc_u4(a0, u0); acc_u4(a1, u1); acc_u4(a0, u2); acc_u4(a1, u3);
        acc_u4(a0, u4); acc_u4(a1, u5); acc_u4(a0, u6); acc_u4(a1, u7);
    }
    for (; j + 4 <= c; j += 4) {
        const int4 e4 = *reinterpret_cast<const int4*>(er + j);
        uint4 u0 = *reinterpret_cast<const uint4*>(base + (size_t)e4.x * HID_DIM);
        uint4 u1 = *reinterpret_cast<const uint4*>(base + (size_t)e4.y * HID_DIM);
        uint4 u2 = *reinterpret_cast<const uint4*>(base + (size_t)e4.z * HID_DIM);
        uint4 u3 = *reinterpret_cast<const uint4*>(base + (size_t)e4.w * HID_DIM);
        acc_u4(a0, u0); acc_u4(a1, u1); acc_u4(a0, u2); acc_u4(a1, u3);
    }
    for (; j < c; ++j) {
        uint4 u = *reinterpret_cast<const uint4*>(base + (size_t)er[j] * HID_DIM);
        acc_u4(a0, u);
    }

    uint4 o;
    o.x = pack2((a0[0] + a1[0]) * r, (a0[1] + a1[1]) * r);
    o.y = pack2((a0[2] + a1[2]) * r, (a0[3] + a1[3]) * r);
    o.z = pack2((a0[4] + a1[4]) * r, (a0[5] + a1[5]) * r);
    o.w = pack2((a0[6] + a1[6]) * r, (a0[7] + a1[7]) * r);
    *reinterpret_cast<uint4*>(Mb + (size_t)node * HID_DIM + lane * 8) = o;
}

// ---------------------------------------------------------------------------
// K5: fused layer-2 GEMM + output GEMM.
//     Phase 1: h2 = relu(m2b @ wp2 + b2) masked -> LDS (bf16, stride 136)
//     Phase 2: out = h2 @ wpo + bout (fp32)
// ---------------------------------------------------------------------------
#define H2S (HID_DIM + 8)
__global__ __launch_bounds__(256) void k_mgemm23(const unsigned short* __restrict__ A,
                                                 const unsigned short* __restrict__ Wp2g,
                                                 const unsigned short* __restrict__ Wpog,
                                                 const float* __restrict__ b2,
                                                 const float* __restrict__ bout,
                                                 const int* __restrict__ cnt,
                                                 float* __restrict__ out) {
    __shared__ unsigned short Wp2s[HID_DIM * HID_DIM];   // 32 KB
    __shared__ unsigned short Wpos[HID_DIM * OUT_DIM];   //  8 KB
    __shared__ unsigned short h2s[64 * H2S];             // 17 KB
    const int tid = threadIdx.x;
#pragma unroll
    for (int f = tid; f < HID_DIM * HID_DIM / 8; f += 256)
        reinterpret_cast<uint4*>(Wp2s)[f] = reinterpret_cast<const uint4*>(Wp2g)[f];
#pragma unroll
    for (int f = tid; f < HID_DIM * OUT_DIM / 8; f += 256)
        reinterpret_cast<uint4*>(Wpos)[f] = reinterpret_cast<const uint4*>(Wpog)[f];
    __syncthreads();

    const int w  = tid >> 6;
    const int l  = tid & 63;
    const int lr = l & 15;
    const int lg = l >> 4;
    const int row = blockIdx.x * 64 + w * 16 + lr;
    const bool rok = row < N_NODES;
    const unsigned short* Arow = A + (size_t)row * HID_DIM;

    fx4_t acc[8];
#pragma unroll
    for (int ct = 0; ct < 8; ++ct) acc[ct] = (fx4_t){0.f, 0.f, 0.f, 0.f};

#pragma unroll
    for (int kc = 0; kc < HID_DIM; kc += 32) {
        bh8_t af = {};
        if (rok) af = *reinterpret_cast<const bh8_t*>(Arow + kc + lg * 8);
#pragma unroll
        for (int ct = 0; ct < 8; ++ct) {
            const bh8_t bf = *reinterpret_cast<const bh8_t*>(
                &Wp2s[(((kc >> 3) + lg) * HID_DIM + ct * 16 + lr) * 8]);
            acc[ct] = __builtin_amdgcn_mfma_f32_16x16x32_bf16(af, bf, acc[ct], 0, 0, 0);
        }
    }

    const int lrow0 = w * 16 + lg * 4;
    const int orow0 = blockIdx.x * 64 + lrow0;
    bool on[4];
#pragma unroll
    for (int r = 0; r < 4; ++r)
        on[r] = (orow0 + r < N_NODES) && (cnt[orow0 + r] > 0);

#pragma unroll
    for (int ct = 0; ct < 8; ++ct) {
        const int m = ct * 16 + lr;
        const float bm = b2[m];
#pragma unroll
        for (int r = 0; r < 4; ++r) {
            float v = on[r] ? fmaxf(acc[ct][r] + bm, 0.f) : 0.f;
            h2s[(lrow0 + r) * H2S + m] = f2bf(v);
        }
    }
    __syncthreads();

    fx4_t acc2[2];
#pragma unroll
    for (int ct = 0; ct < 2; ++ct) acc2[ct] = (fx4_t){0.f, 0.f, 0.f, 0.f};

#pragma unroll
    for (int kc = 0; kc < HID_DIM; kc += 32) {
        const bh8_t af = *reinterpret_cast<const bh8_t*>(
            &h2s[(w * 16 + lr) * H2S + kc + lg * 8]);
#pragma unroll
        for (int ct = 0; ct < 2; ++ct) {
            const bh8_t bf = *reinterpret_cast<const bh8_t*>(
                &Wpos[(((kc >> 3) + lg) * OUT_DIM + ct * 16 + lr) * 8]);
            acc2[ct] = __builtin_amdgcn_mfma_f32_16x16x32_bf16(af, bf, acc2[ct], 0, 0, 0);
        }
    }

#pragma unroll
    for (int ct = 0; ct < 2; ++ct) {
        const int m = ct * 16 + lr;
        const float bm = bout[m];
#pragma unroll
        for (int r = 0; r < 4; ++r) {
            const int n = orow0 + r;
            if (n < N_NODES)
                out[(size_t)n * OUT_DIM + m] = acc2[ct][r] + bm;
        }
    }
}

// ---------------------------------------------------------------------------
extern "C" void kernel_launch(void* const* d_in, const int* in_sizes, int n_in,
                              void* d_out, int out_size, void* d_ws, size_t ws_size,
                              hipStream_t stream) {
    const float* x    = (const float*)d_in[0];
    const int*   ei   = (const int*)d_in[1];
    const float* W1   = (const float*)d_in[2];
    const float* b1   = (const float*)d_in[3];
    const float* W2   = (const float*)d_in[4];
    const float* b2   = (const float*)d_in[5];
    const float* Wout = (const float*)d_in[6];
    const float* bout = (const float*)d_in[7];
    float* out = (float*)d_out;

    const int* src = ei;
    const int* dst = ei + N_EDGES;

    // workspace layout (16B aligned)
    char* ws = (char*)d_ws;
    int*            cnt = (int*)(ws + 0);                    //    200,000
    int*            ell = (int*)(ws + 200000);               // 12,800,000 -> 13,000,000
    unsigned short* xb  = (unsigned short*)(ws + 13000000);  //  6,400,000 -> 19,400,000
    unsigned short* h1b = (unsigned short*)(ws + 19400000);  // 12,800,000 -> 32,200,000
    unsigned short* m2b = (unsigned short*)(ws + 32200000);  // 12,800,000 -> 45,000,000
    unsigned short* m1b = (unsigned short*)(ws + 45000000);  //  6,400,000 -> 51,400,000
    unsigned short* wp1 = (unsigned short*)(ws + 51400000);  //    16,384 -> 51,416,384
    unsigned short* wp2 = (unsigned short*)(ws + 51416384);  //    32,768 -> 51,449,152
    unsigned short* wpo = (unsigned short*)(ws + 51449152);  //     8,192 -> 51,457,344

    const int GB = (N_NODES + 63) / 64;          // 782
    const int AB = N_NODES / 16;                 // 3125

    // prep: cast + weight packing + cnt zeroing (all independent of scatter)
    k_prep<<<CAST_BLKS + PW1_BLKS + PW2_BLKS + PWO_BLKS + ZERO_BLKS, 256, 0, stream>>>(
        x, xb, W1, wp1, W2, wp2, Wout, wpo, cnt);

    // ELL scatter, isolated (round-7 champion variant)
    k_ell<<<FILL_NJ * NRANGE, 256, 0, stream>>>(src, dst, cnt, ell);

    // layer 1: aggregate then GEMM (split — fused version was latency-bound)
    k_agg1<<<AB, 256, 0, stream>>>(xb, ell, cnt, m1b);
    k_mgemm1<<<GB, 256, 0, stream>>>(m1b, wp1, b1, cnt, h1b);

    // layer 2 aggregation
    k_agg2<<<AB, 256, 0, stream>>>(h1b, ell, cnt, m2b);

    // fused layer-2 GEMM + output GEMM
    k_mgemm23<<<GB, 256, 0, stream>>>(m2b, wp2, wpo, b2, bout, cnt, out);
}